// Round 2
// baseline (454.362 us; speedup 1.0000x reference)
//
#include <hip/hip_runtime.h>
#include <math.h>

// ---------------- problem constants ----------------
#define FC     65            // freq bins in H
#define NB     97            // output samples per frame (lossy irfft n)
#define KB     49            // bins actually used = NB//2+1
#define FRAME  64
#define B_     32
#define F_     4000
#define OUT_LEN ((F_ - 1) * FRAME + NB)   // 256033
#define CHUNK  63                          // OUTPUT frames per block (lane0 redundant)
#define NCHUNK ((F_ + CHUNK - 1) / CHUNK)  // 64
#define KP     98                          // row stride: 49 complex = 98 floats

// ws layout (floats):
//   D: [64][98]  row j: (cos,sin)(-2*pi*k*j/192) pairs, k=0..48
//   W: [65][98]  row kappa: complex of sum_m a(m,kappa) e^{-2pi i k m/192}
//   E: [97][98]  row t: (Er, Ei) pairs, gain folded in
#define D_OFF  0
#define W_OFF  (64 * KP)                   // 6272
#define E_OFF  (W_OFF + 65 * KP)           // 12642

#define N_D    (64 * KB)                   // 3136
#define N_E    (97 * KB)                   // 4753
#define N_MISC (N_D + N_E)                 // 7889

// ---------- init: D and E, one thread per element, cospi/sinpi ----------
__global__ void fn_init_misc(float* __restrict__ ws) {
    int tid = blockIdx.x * blockDim.x + threadIdx.x;
    if (tid < N_D) {
        int j = tid / KB, k = tid % KB;
        double x = -(double)(k * j) / 96.0;          // theta/pi
        ws[D_OFF + j * KP + 2 * k]     = (float)cospi(x);
        ws[D_OFF + j * KP + 2 * k + 1] = (float)sinpi(x);
    } else if (tid < N_MISC) {
        int t2 = tid - N_D;
        int t = t2 / KB, k = t2 % KB;
        double g = 0.01 / 97.0;
        double x = 2.0 * (double)(k * t) / 97.0;     // theta/pi
        double c = cospi(x), s = sinpi(x);
        ws[E_OFF + t * KP + 2 * k]     = (float)(g * (k == 0 ? 1.0 : 2.0) * c);
        ws[E_OFF + t * KP + 2 * k + 1] = (float)(k == 0 ? 0.0 : -g * 2.0 * s);
    }
}

// ---------- init: W, one block (wave) per (kappa,k), parallel over m ----------
__global__ __launch_bounds__(64) void fn_init_w(float* __restrict__ ws) {
    int blk = blockIdx.x;                 // 0..65*49-1
    int kap = blk / KB, k = blk % KB;
    int L = threadIdx.x;
    double sr = 0.0, si = 0.0;
    for (int m = L; m < 129; m += 64) {
        double win = 0.5 * (1.0 - cospi(2.0 * (double)m / 129.0));
        double a = win * (1.0 / 129.0);
        if (kap) a *= 2.0 * cospi(2.0 * (double)(kap * (m - 64)) / 129.0);
        double x = -(double)(k * m) / 96.0;           // theta/pi
        sr += a * cospi(x);
        si += a * sinpi(x);
    }
    for (int off = 32; off; off >>= 1) {
        sr += __shfl_down(sr, off);
        si += __shfl_down(si, off);
    }
    if (L == 0) {
        ws[W_OFF + kap * KP + 2 * k]     = (float)sr;
        ws[W_OFF + kap * KP + 2 * k + 1] = (float)si;
    }
}

// ---------- main ----------
__launch_bounds__(64, 2)
__global__ void fn_main_kernel(const float* __restrict__ H,
                               const float* __restrict__ noise,
                               const float* __restrict__ ws,
                               float* __restrict__ out) {
    // lds layout: stage[4160] (noise 64x65-pad -> H linear -> obuf 63x66-pad),
    //             ybuf[64*34]
    __shared__ float lds[4160 + 64 * 34];
    float* stage = lds;
    float* ybuf  = lds + 4160;

    int bid = blockIdx.x;
    int b = bid / NCHUNK;
    int c = bid % NCHUNK;
    int f0 = c * CHUNK;                   // first OUTPUT frame of this block
    int nf = min(CHUNK, F_ - f0);         // frames this block outputs
    int L = threadIdx.x;                  // lane computes frame f0-1+L
    int fMine = f0 - 1 + L;

    // ---- phase 0: stage noise frames f0-1 .. f0+62 (row i = frame f0-1+i) ----
    long nbase = ((long)b * F_ + (f0 - 1)) * FRAME;
    long nmax = (long)B_ * F_ * FRAME - 1;
    for (int i = 0; i < 64; i++) {
        long g = nbase + (long)i * 64 + L;
        if (g < 0) g = 0;
        if (g > nmax) g = nmax;
        stage[i * 65 + L] = 2.0f * noise[g] - 1.0f;
    }
    __syncthreads();

    // ---- phase 1: N[k] = DFT_192 of my frame's 64 samples, bins 0..48 ----
    float Nr[KB], Ni[KB];
#pragma unroll
    for (int k = 0; k < KB; k++) { Nr[k] = 0.0f; Ni[k] = 0.0f; }
    for (int j = 0; j < 64; j++) {
        float n = stage[L * 65 + j];
        const float* d = ws + D_OFF + j * KP;
#pragma unroll
        for (int k = 0; k < KB; k++) {
            Nr[k] = fmaf(n, d[2 * k],     Nr[k]);
            Ni[k] = fmaf(n, d[2 * k + 1], Ni[k]);
        }
    }
    __syncthreads();

    // ---- phase 2: stage H (linear copy, 64 frames x 65 = 4160 floats) ----
    long hbase = ((long)b * F_ + (f0 - 1)) * FC;
    long hmax = (long)B_ * F_ * FC - 1;
    for (int i = 0; i < 65; i++) {
        long g = hbase + (long)i * 64 + L;
        if (g < 0) g = 0;
        if (g > hmax) g = hmax;
        stage[i * 64 + L] = H[g];
    }
    __syncthreads();

    // ---- phase 3: IR[k] = W . H ----
    float Rr[KB], Ri[KB];
#pragma unroll
    for (int k = 0; k < KB; k++) { Rr[k] = 0.0f; Ri[k] = 0.0f; }
    for (int kap = 0; kap < FC; kap++) {
        float h = stage[L * FC + kap];
        const float* w = ws + W_OFF + kap * KP;
#pragma unroll
        for (int k = 0; k < KB; k++) {
            Rr[k] = fmaf(h, w[2 * k],     Rr[k]);
            Ri[k] = fmaf(h, w[2 * k + 1], Ri[k]);
        }
    }

    // ---- phase 4: X = N * IR (complex), in place into Nr/Ni ----
#pragma unroll
    for (int k = 0; k < KB; k++) {
        float xr = Nr[k] * Rr[k] - Ni[k] * Ri[k];
        float xi = Nr[k] * Ri[k] + Ni[k] * Rr[k];
        Nr[k] = xr; Ni[k] = xi;
    }
    // lane 0 of chunk 0 represents frame -1: contributes nothing
    if (c == 0 && L == 0) {
#pragma unroll
        for (int k = 0; k < KB; k++) { Nr[k] = 0.0f; Ni[k] = 0.0f; }
    }
    __syncthreads();   // H staging dead; stage[] becomes obuf (63 x 66)

    // ---- phase 5: y[t] = E[t] . X; overlap-add resolved in-wave ----
    bool valid = (L >= 1) && (fMine <= F_ - 1);
    long bOut = (long)b * OUT_LEN;

    for (int t = 0; t < NB; t++) {
        const float* e = ws + E_OFF + t * KP;
        float y0 = 0.0f, y1 = 0.0f, y2 = 0.0f, y3 = 0.0f;
#pragma unroll
        for (int k = 0; k < 48; k += 4) {
            y0 = fmaf(Nr[k],     e[2 * k],     y0); y0 = fmaf(Ni[k],     e[2 * k + 1], y0);
            y1 = fmaf(Nr[k + 1], e[2 * k + 2], y1); y1 = fmaf(Ni[k + 1], e[2 * k + 3], y1);
            y2 = fmaf(Nr[k + 2], e[2 * k + 4], y2); y2 = fmaf(Ni[k + 2], e[2 * k + 5], y2);
            y3 = fmaf(Nr[k + 3], e[2 * k + 6], y3); y3 = fmaf(Ni[k + 3], e[2 * k + 7], y3);
        }
        y0 = fmaf(Nr[48], e[96], y0);
        y0 = fmaf(Ni[48], e[97], y0);
        float y = (y0 + y1) + (y2 + y3);

        if (t < 33) {
            // head samples: buffered, combined with prev frame's tail later
            ybuf[L * 34 + t] = y;
        } else if (t < 64) {
            // exclusive samples: straight into obuf
            if (valid) stage[(L - 1) * 66 + t] = y;
        } else {
            int r = t - 64;
            float p = __shfl_up(y, 1);             // frame fMine-1's tail sample
            if (valid) stage[(L - 1) * 66 + r] = ybuf[L * 34 + r] + p;
            // very last frame: its tail lands past all frame starts — store direct
            if (fMine == F_ - 1) out[bOut + (long)(F_ - 1) * FRAME + t] = y;
        }
    }
    __syncthreads();

    // ---- phase 6: coalesced store, 256B per instruction ----
    long obase2 = bOut + (long)f0 * FRAME;
    for (int i = 0; i < nf; i++) {
        out[obase2 + (long)i * 64 + L] = stage[i * 66 + L];
    }
}

extern "C" void kernel_launch(void* const* d_in, const int* in_sizes, int n_in,
                              void* d_out, int out_size, void* d_ws, size_t ws_size,
                              hipStream_t stream) {
    const float* H     = (const float*)d_in[0];   // (32, 4000, 65) fp32
    const float* noise = (const float*)d_in[1];   // (32, 4000, 64) fp32
    float* out = (float*)d_out;                   // (32, 256033) fp32
    float* ws  = (float*)d_ws;                    // matrices, 22148 floats

    fn_init_misc<<<(N_MISC + 255) / 256, 256, 0, stream>>>(ws);
    fn_init_w<<<FC * KB, 64, 0, stream>>>(ws);

    fn_main_kernel<<<B_ * NCHUNK, 64, 0, stream>>>(H, noise, ws, out);
}

// Round 3
// 374.776 us; speedup vs baseline: 1.2124x; 1.2124x over previous
//
#include <hip/hip_runtime.h>
#include <math.h>

// ---------------- problem constants ----------------
#define FC     65            // freq bins in H
#define NB     97            // output samples per frame (lossy irfft n)
#define KB     49            // bins actually used = NB//2+1
#define FRAME  64
#define B_     32
#define F_     4000
#define OUT_LEN ((F_ - 1) * FRAME + NB)   // 256033
#define CHUNK  63                          // OUTPUT frames per block (lane0 redundant)
#define NCHUNK 64                          // ceil(4000/63)
#define KP     98                          // row stride: 49 complex = 98 floats

// ws layout (floats):
//   D: [64][98]  row j:   (cos,sin)(-2*pi*k*j/192) pairs, k=0..48
//   W: [65][98]  row kap: complex of sum_m a(m,kap) e^{-2pi i k m/192}
//   E: [97][98]  row t:   (Er, Ei) pairs, gain folded in
#define D_OFF  0
#define W_OFF  (64 * KP)
#define E_OFF  (W_OFF + 65 * KP)

#define N_D    (64 * KB)                   // 3136
#define N_E    (97 * KB)                   // 4753
#define N_W    (65 * KB)                   // 3185
#define N_ALL  (N_D + N_E + N_W)           // 11074

// ---------- single init kernel; W via fp64 recurrences (no libm in loop) ----------
__global__ void fn_init(float* __restrict__ ws) {
    int tid = blockIdx.x * blockDim.x + threadIdx.x;
    if (tid < N_D) {
        int j = tid / KB, k = tid % KB;
        double x = -(double)(k * j) / 96.0;            // theta/pi
        ws[D_OFF + j * KP + 2 * k]     = (float)cospi(x);
        ws[D_OFF + j * KP + 2 * k + 1] = (float)sinpi(x);
    } else if (tid < N_D + N_E) {
        int t2 = tid - N_D;
        int t = t2 / KB, k = t2 % KB;
        double g = 0.01 / 97.0;
        double x = 2.0 * (double)(k * t) / 97.0;       // theta/pi
        ws[E_OFF + t * KP + 2 * k]     = (float)(g * (k == 0 ? 1.0 : 2.0) * cospi(x));
        ws[E_OFF + t * KP + 2 * k + 1] = (float)(k == 0 ? 0.0 : -2.0 * g * sinpi(x));
    } else if (tid < N_ALL) {
        int t2 = tid - (N_D + N_E);
        int kap = t2 / KB, k = t2 % KB;
        // e(k,m) = exp(-2pi i k m/192); rotation step
        double sr_ = cospi(-(double)k / 96.0), si_ = sinpi(-(double)k / 96.0);
        double er = 1.0, ei = 0.0;
        // c(kap,m) = cos(2pi kap (m-64)/129), Chebyshev recurrence
        double C2 = 2.0 * cospi(2.0 * (double)kap / 129.0);
        double c_prev = cospi(-130.0 * (double)kap / 129.0);   // m = -1
        double c_cur  = cospi(-128.0 * (double)kap / 129.0);   // m = 0
        // u(m) = cos(2pi m/129) for the hann window
        double U2 = 2.0 * cospi(2.0 / 129.0);
        double u_prev = cospi(2.0 / 129.0);                    // u(-1)
        double u_cur  = 1.0;                                   // u(0)
        double accr = 0.0, acci = 0.0;
        for (int m = 0; m < 129; m++) {
            double win = 0.5 * (1.0 - u_cur);
            double a = win * (1.0 / 129.0);
            if (kap) a *= 2.0 * c_cur;
            accr += a * er; acci += a * ei;
            double un = U2 * u_cur - u_prev; u_prev = u_cur; u_cur = un;
            double cn = C2 * c_cur - c_prev; c_prev = c_cur; c_cur = cn;
            double e2r = er * sr_ - ei * si_;
            double e2i = er * si_ + ei * sr_;
            er = e2r; ei = e2i;
        }
        ws[W_OFF + kap * KP + 2 * k]     = (float)accr;
        ws[W_OFF + kap * KP + 2 * k + 1] = (float)acci;
    }
}

// ---------- main: 1 wave/block, 64 frames (63 output + 1 redundant) ----------
__launch_bounds__(64, 2)
__global__ void fn_main_kernel(const float* __restrict__ H,
                               const float* __restrict__ noise,
                               const float* __restrict__ ws,
                               float* __restrict__ out) {
    __shared__ float bufA[64 * 65];       // 16.6 KB, reused: noise -> H -> obuf

    int bid = blockIdx.x;
    int b = bid >> 6;                     // NCHUNK = 64
    int c = bid & 63;
    int f0 = c * CHUNK;
    int nf = min(CHUNK, F_ - f0);
    int L = threadIdx.x;                  // lane computes frame f0-1+L
    int fMine = f0 - 1 + L;

    // ---- phase 0: stage noise frames f0-1 .. f0+62 (row i, stride 65) ----
    long nbase = ((long)b * F_ + (f0 - 1)) * FRAME;
    const long nmax = (long)B_ * F_ * FRAME - 1;
#pragma unroll 1
    for (int i = 0; i < 64; i++) {
        long g = nbase + (long)i * 64 + L;
        g = g < 0 ? 0 : (g > nmax ? nmax : g);
        float v = 2.0f * noise[g] - 1.0f;
        if (c == 0 && i == 0) v = 0.0f;   // frame -1: force N=0 -> X=0
        bufA[i * 65 + L] = v;
    }
    __syncthreads();

    // ---- phase 1: N[k] = DFT_192 of my frame (bins 0..48) ----
    float Nr[KB], Ni[KB];
#pragma unroll
    for (int k = 0; k < KB; k++) { Nr[k] = 0.0f; Ni[k] = 0.0f; }
#pragma unroll 1
    for (int j = 0; j < 64; j++) {
        float n = bufA[L * 65 + j];
        const float* d = ws + D_OFF + j * KP;
#pragma unroll
        for (int k = 0; k < KB; k++) {
            Nr[k] = fmaf(n, d[2 * k],     Nr[k]);
            Ni[k] = fmaf(n, d[2 * k + 1], Ni[k]);
        }
    }
    __syncthreads();

    // ---- phase 2: stage H (straight linear copy; rows = frames, stride 65) ----
    long hbase = ((long)b * F_ + (f0 - 1)) * FC;
    const long hmax = (long)B_ * F_ * FC - 1;
#pragma unroll 1
    for (int i = 0; i < 65; i++) {
        long g = hbase + (long)i * 64 + L;
        g = g < 0 ? 0 : (g > hmax ? hmax : g);
        bufA[i * 64 + L] = H[g];
    }
    __syncthreads();

    // ---- phase 3+4 fused, k-tiles of 7: R-tile = W.h, then X = N*R in place ----
#pragma unroll 1
    for (int tile = 0; tile < 7; tile++) {
        int k0 = tile * 7;
        float Rr[7], Ri[7];
#pragma unroll
        for (int kk = 0; kk < 7; kk++) { Rr[kk] = 0.0f; Ri[kk] = 0.0f; }
        const float* wbase = ws + W_OFF + 2 * k0;
#pragma unroll 1
        for (int kap = 0; kap < FC; kap++) {
            float h = bufA[L * FC + kap];
            const float* w = wbase + kap * KP;
#pragma unroll
            for (int kk = 0; kk < 7; kk++) {
                Rr[kk] = fmaf(h, w[2 * kk],     Rr[kk]);
                Ri[kk] = fmaf(h, w[2 * kk + 1], Ri[kk]);
            }
        }
#pragma unroll
        for (int kk = 0; kk < 7; kk++) {
            int k = k0 + kk;
            float xr = Nr[k] * Rr[kk] - Ni[k] * Ri[kk];
            float xi = Nr[k] * Ri[kk] + Ni[k] * Rr[kk];
            Nr[k] = xr; Ni[k] = xi;
        }
    }
    __syncthreads();                      // H dead; bufA becomes obuf (rows stride 65)

    // ---- phase 5: y[t] = E[t].X ; overlap-add resolved in-wave via obuf RMW ----
#pragma unroll 1
    for (int t = 0; t < 64; t++) {
        const float* e = ws + E_OFF + t * KP;
        float y0 = 0.0f, y1 = 0.0f, y2 = 0.0f, y3 = 0.0f;
#pragma unroll
        for (int k = 0; k < 48; k += 4) {
            y0 = fmaf(Nr[k],     e[2 * k],     y0); y0 = fmaf(Ni[k],     e[2 * k + 1], y0);
            y1 = fmaf(Nr[k + 1], e[2 * k + 2], y1); y1 = fmaf(Ni[k + 1], e[2 * k + 3], y1);
            y2 = fmaf(Nr[k + 2], e[2 * k + 4], y2); y2 = fmaf(Ni[k + 2], e[2 * k + 5], y2);
            y3 = fmaf(Nr[k + 3], e[2 * k + 6], y3); y3 = fmaf(Ni[k + 3], e[2 * k + 7], y3);
        }
        y0 = fmaf(Nr[48], e[96], y0);
        y0 = fmaf(Ni[48], e[97], y0);
        float y = (y0 + y1) + (y2 + y3);
        if (L) bufA[(L - 1) * 65 + t] = y;
    }
#pragma unroll 1
    for (int t = 64; t < 97; t++) {
        const float* e = ws + E_OFF + t * KP;
        float y0 = 0.0f, y1 = 0.0f, y2 = 0.0f, y3 = 0.0f;
#pragma unroll
        for (int k = 0; k < 48; k += 4) {
            y0 = fmaf(Nr[k],     e[2 * k],     y0); y0 = fmaf(Ni[k],     e[2 * k + 1], y0);
            y1 = fmaf(Nr[k + 1], e[2 * k + 2], y1); y1 = fmaf(Ni[k + 1], e[2 * k + 3], y1);
            y2 = fmaf(Nr[k + 2], e[2 * k + 4], y2); y2 = fmaf(Ni[k + 2], e[2 * k + 5], y2);
            y3 = fmaf(Nr[k + 3], e[2 * k + 6], y3); y3 = fmaf(Ni[k + 3], e[2 * k + 7], y3);
        }
        y0 = fmaf(Nr[48], e[96], y0);
        y0 = fmaf(Ni[48], e[97], y0);
        float y = (y0 + y1) + (y2 + y3);

        int r = t - 64;
        float p = __shfl_up(y, 1);                    // prev frame's tail sample
        if (L) bufA[(L - 1) * 65 + r] += p;           // head + prev tail
        if (fMine == F_ - 1)                          // global last frame's tail
            out[(long)b * OUT_LEN + (long)(F_ - 1) * FRAME + t] = y;
    }
    __syncthreads();

    // ---- phase 6: coalesced 256B wave stores ----
    long obase2 = (long)b * OUT_LEN + (long)f0 * FRAME;
#pragma unroll 1
    for (int i = 0; i < nf; i++) {
        out[obase2 + (long)i * 64 + L] = bufA[i * 65 + L];
    }
}

extern "C" void kernel_launch(void* const* d_in, const int* in_sizes, int n_in,
                              void* d_out, int out_size, void* d_ws, size_t ws_size,
                              hipStream_t stream) {
    const float* H     = (const float*)d_in[0];   // (32, 4000, 65) fp32
    const float* noise = (const float*)d_in[1];   // (32, 4000, 64) fp32
    float* out = (float*)d_out;                   // (32, 256033) fp32
    float* ws  = (float*)d_ws;                    // matrices, 22148 floats

    fn_init<<<(N_ALL + 255) / 256, 256, 0, stream>>>(ws);
    fn_main_kernel<<<B_ * NCHUNK, 64, 0, stream>>>(H, noise, ws, out);
}

// Round 4
// 371.230 us; speedup vs baseline: 1.2239x; 1.0096x over previous
//
#include <hip/hip_runtime.h>
#include <math.h>

// ---------------- problem constants ----------------
#define FC     65            // freq bins in H
#define NB     97            // output samples per frame (lossy irfft n)
#define KB     49            // bins actually used = NB//2+1
#define FRAME  64
#define B_     32
#define F_     4000
#define OUT_LEN ((F_ - 1) * FRAME + NB)   // 256033
#define CHUNK  63                          // OUTPUT frames per block (lane0 redundant)
#define NCHUNK 64                          // ceil(4000/63)
#define KP     98                          // row stride: 49 complex = 98 floats

// ws layout (floats):
//   D: [64][98]  row j:   (cos,sin)(-2*pi*k*j/192) pairs, k=0..48
//   W: [65][98]  row kap: complex of sum_m a(m,kap) e^{-2pi i k m/192}
//   E: [97][98]  row t:   (Er, Ei) pairs, gain folded in
#define D_OFF  0
#define W_OFF  (64 * KP)
#define E_OFF  (W_OFF + 65 * KP)

#define N_D    (64 * KB)                   // 3136
#define N_E    (97 * KB)                   // 4753
#define N_W    (65 * KB)                   // 3185
#define N_ALL  (N_D + N_E + N_W)           // 11074

// ---------- single init kernel; W via fp64 recurrences (no libm in loop) ----------
__global__ void fn_init(float* __restrict__ ws) {
    int tid = blockIdx.x * blockDim.x + threadIdx.x;
    if (tid < N_D) {
        int j = tid / KB, k = tid % KB;
        double x = -(double)(k * j) / 96.0;            // theta/pi
        ws[D_OFF + j * KP + 2 * k]     = (float)cospi(x);
        ws[D_OFF + j * KP + 2 * k + 1] = (float)sinpi(x);
    } else if (tid < N_D + N_E) {
        int t2 = tid - N_D;
        int t = t2 / KB, k = t2 % KB;
        double g = 0.01 / 97.0;
        double x = 2.0 * (double)(k * t) / 97.0;       // theta/pi
        ws[E_OFF + t * KP + 2 * k]     = (float)(g * (k == 0 ? 1.0 : 2.0) * cospi(x));
        ws[E_OFF + t * KP + 2 * k + 1] = (float)(k == 0 ? 0.0 : -2.0 * g * sinpi(x));
    } else if (tid < N_ALL) {
        int t2 = tid - (N_D + N_E);
        int kap = t2 / KB, k = t2 % KB;
        // e(k,m) = exp(-2pi i k m/192); rotation step
        double sr_ = cospi(-(double)k / 96.0), si_ = sinpi(-(double)k / 96.0);
        double er = 1.0, ei = 0.0;
        // c(kap,m) = cos(2pi kap (m-64)/129), Chebyshev recurrence
        double C2 = 2.0 * cospi(2.0 * (double)kap / 129.0);
        double c_prev = cospi(-130.0 * (double)kap / 129.0);   // m = -1
        double c_cur  = cospi(-128.0 * (double)kap / 129.0);   // m = 0
        // u(m) = cos(2pi m/129) for the hann window
        double U2 = 2.0 * cospi(2.0 / 129.0);
        double u_prev = cospi(2.0 / 129.0);                    // u(-1)
        double u_cur  = 1.0;                                   // u(0)
        double accr = 0.0, acci = 0.0;
        for (int m = 0; m < 129; m++) {
            double win = 0.5 * (1.0 - u_cur);
            double a = win * (1.0 / 129.0);
            if (kap) a *= 2.0 * c_cur;
            accr += a * er; acci += a * ei;
            double un = U2 * u_cur - u_prev; u_prev = u_cur; u_cur = un;
            double cn = C2 * c_cur - c_prev; c_prev = c_cur; c_cur = cn;
            double e2r = er * sr_ - ei * si_;
            double e2i = er * si_ + ei * sr_;
            er = e2r; ei = e2i;
        }
        ws[W_OFF + kap * KP + 2 * k]     = (float)accr;
        ws[W_OFF + kap * KP + 2 * k + 1] = (float)acci;
    }
}

// ---------- main: 1 wave/block, 64 frames (63 output + 1 redundant) ----------
__launch_bounds__(64, 2)
__global__ void fn_main_kernel(const float* __restrict__ H,
                               const float* __restrict__ noise,
                               const float* __restrict__ ws,
                               float* __restrict__ out) {
    __shared__ float bufA[64 * 65];       // 16.6 KB, reused: noise -> H -> obuf

    int bid = blockIdx.x;
    int b = bid >> 6;                     // NCHUNK = 64
    int c = bid & 63;
    int f0 = c * CHUNK;
    int nf = min(CHUNK, F_ - f0);
    int L = threadIdx.x;                  // lane computes frame f0-1+L
    int fMine = f0 - 1 + L;

    // ---- phase 0: stage noise frames f0-1 .. f0+62 (row i, stride 65) ----
    long nbase = ((long)b * F_ + (f0 - 1)) * FRAME;
    const long nmax = (long)B_ * F_ * FRAME - 1;
#pragma unroll 1
    for (int i = 0; i < 64; i++) {
        long g = nbase + (long)i * 64 + L;
        g = g < 0 ? 0 : (g > nmax ? nmax : g);
        float v = 2.0f * noise[g] - 1.0f;
        if (c == 0 && i == 0) v = 0.0f;   // frame -1: force N=0 -> X=0
        bufA[i * 65 + L] = v;
    }
    __syncthreads();

    // ---- phase 1: N[k] = DFT_192 of my frame (bins 0..48) ----
    float Nr[KB], Ni[KB];
#pragma unroll
    for (int k = 0; k < KB; k++) { Nr[k] = 0.0f; Ni[k] = 0.0f; }
#pragma unroll 1
    for (int j = 0; j < 64; j++) {
        float n = bufA[L * 65 + j];
        const float* d = ws + D_OFF + j * KP;
#pragma unroll
        for (int k = 0; k < KB; k++) {
            Nr[k] = fmaf(n, d[2 * k],     Nr[k]);
            Ni[k] = fmaf(n, d[2 * k + 1], Ni[k]);
        }
    }
    __syncthreads();

    // ---- phase 2: stage H (straight linear copy; rows = frames, stride 65) ----
    long hbase = ((long)b * F_ + (f0 - 1)) * FC;
    const long hmax = (long)B_ * F_ * FC - 1;
#pragma unroll 1
    for (int i = 0; i < 65; i++) {
        long g = hbase + (long)i * 64 + L;
        g = g < 0 ? 0 : (g > hmax ? hmax : g);
        bufA[i * 64 + L] = H[g];
    }
    __syncthreads();

    // ---- phase 3+4 fused, k-tiles of 7, FULLY UNROLLED so every Nr/Ni index
    // is a compile-time constant (runtime-indexed access demotes X to scratch:
    // that was round 3's 182MB-WRITE_SIZE spill) ----
#pragma unroll
    for (int tile = 0; tile < 7; tile++) {
        const int k0 = tile * 7;
        float Rr[7], Ri[7];
#pragma unroll
        for (int kk = 0; kk < 7; kk++) { Rr[kk] = 0.0f; Ri[kk] = 0.0f; }
        const float* wbase = ws + W_OFF + 2 * k0;
#pragma unroll 1
        for (int kap = 0; kap < FC; kap++) {
            float h = bufA[L * FC + kap];
            const float* w = wbase + kap * KP;
#pragma unroll
            for (int kk = 0; kk < 7; kk++) {
                Rr[kk] = fmaf(h, w[2 * kk],     Rr[kk]);
                Ri[kk] = fmaf(h, w[2 * kk + 1], Ri[kk]);
            }
        }
#pragma unroll
        for (int kk = 0; kk < 7; kk++) {
            const int k = k0 + kk;
            float xr = Nr[k] * Rr[kk] - Ni[k] * Ri[kk];
            float xi = Nr[k] * Ri[kk] + Ni[k] * Rr[kk];
            Nr[k] = xr; Ni[k] = xi;
        }
    }
    __syncthreads();                      // H dead; bufA becomes obuf (rows stride 65)

    // ---- phase 5: y[t] = E[t].X ; overlap-add resolved in-wave via obuf RMW ----
#pragma unroll 1
    for (int t = 0; t < 64; t++) {
        const float* e = ws + E_OFF + t * KP;
        float y0 = 0.0f, y1 = 0.0f, y2 = 0.0f, y3 = 0.0f;
#pragma unroll
        for (int k = 0; k < 48; k += 4) {
            y0 = fmaf(Nr[k],     e[2 * k],     y0); y0 = fmaf(Ni[k],     e[2 * k + 1], y0);
            y1 = fmaf(Nr[k + 1], e[2 * k + 2], y1); y1 = fmaf(Ni[k + 1], e[2 * k + 3], y1);
            y2 = fmaf(Nr[k + 2], e[2 * k + 4], y2); y2 = fmaf(Ni[k + 2], e[2 * k + 5], y2);
            y3 = fmaf(Nr[k + 3], e[2 * k + 6], y3); y3 = fmaf(Ni[k + 3], e[2 * k + 7], y3);
        }
        y0 = fmaf(Nr[48], e[96], y0);
        y0 = fmaf(Ni[48], e[97], y0);
        float y = (y0 + y1) + (y2 + y3);
        if (L) bufA[(L - 1) * 65 + t] = y;
    }
#pragma unroll 1
    for (int t = 64; t < 97; t++) {
        const float* e = ws + E_OFF + t * KP;
        float y0 = 0.0f, y1 = 0.0f, y2 = 0.0f, y3 = 0.0f;
#pragma unroll
        for (int k = 0; k < 48; k += 4) {
            y0 = fmaf(Nr[k],     e[2 * k],     y0); y0 = fmaf(Ni[k],     e[2 * k + 1], y0);
            y1 = fmaf(Nr[k + 1], e[2 * k + 2], y1); y1 = fmaf(Ni[k + 1], e[2 * k + 3], y1);
            y2 = fmaf(Nr[k + 2], e[2 * k + 4], y2); y2 = fmaf(Ni[k + 2], e[2 * k + 5], y2);
            y3 = fmaf(Nr[k + 3], e[2 * k + 6], y3); y3 = fmaf(Ni[k + 3], e[2 * k + 7], y3);
        }
        y0 = fmaf(Nr[48], e[96], y0);
        y0 = fmaf(Ni[48], e[97], y0);
        float y = (y0 + y1) + (y2 + y3);

        int r = t - 64;
        float p = __shfl_up(y, 1);                    // prev frame's tail sample
        if (L) bufA[(L - 1) * 65 + r] += p;           // head + prev tail
        if (fMine == F_ - 1)                          // global last frame's tail
            out[(long)b * OUT_LEN + (long)(F_ - 1) * FRAME + t] = y;
    }
    __syncthreads();

    // ---- phase 6: coalesced 256B wave stores ----
    long obase2 = (long)b * OUT_LEN + (long)f0 * FRAME;
#pragma unroll 1
    for (int i = 0; i < nf; i++) {
        out[obase2 + (long)i * 64 + L] = bufA[i * 65 + L];
    }
}

extern "C" void kernel_launch(void* const* d_in, const int* in_sizes, int n_in,
                              void* d_out, int out_size, void* d_ws, size_t ws_size,
                              hipStream_t stream) {
    const float* H     = (const float*)d_in[0];   // (32, 4000, 65) fp32
    const float* noise = (const float*)d_in[1];   // (32, 4000, 64) fp32
    float* out = (float*)d_out;                   // (32, 256033) fp32
    float* ws  = (float*)d_ws;                    // matrices, 22148 floats

    fn_init<<<(N_ALL + 255) / 256, 256, 0, stream>>>(ws);
    fn_main_kernel<<<B_ * NCHUNK, 64, 0, stream>>>(H, noise, ws, out);
}

// Round 5
// 256.247 us; speedup vs baseline: 1.7731x; 1.4487x over previous
//
#include <hip/hip_runtime.h>
#include <math.h>

// ---------------- problem constants ----------------
#define FC     65            // freq bins in H
#define NB     97            // output samples per frame (lossy irfft n)
#define KB     49            // bins actually used = NB//2+1
#define FRAME  64
#define B_     32
#define F_     4000
#define OUT_LEN ((F_ - 1) * FRAME + NB)   // 256033
#define CHUNK  63                          // OUTPUT frames per block (lane0 redundant)
#define NCHUNK 64                          // ceil(4000/63)
#define KP     98                          // row stride: 49 complex = 98 floats

// ws layout (floats):
//   D: [64][98]  row j:   (cos,sin)(-2*pi*k*j/192) pairs, k=0..48
//   W: [65][98]  row kap: complex of sum_m a(m,kap) e^{-2pi i k m/192}
//   E: [97][98]  row t:   (Er, Ei) pairs, gain folded in
#define D_OFF  0
#define W_OFF  (64 * KP)
#define E_OFF  (W_OFF + 65 * KP)

#define N_D    (64 * KB)                   // 3136
#define N_E    (97 * KB)                   // 4753
#define N_W    (65 * KB)                   // 3185
#define N_ALL  (N_D + N_E + N_W)           // 11074

// ---------- single init kernel; W via fp64 recurrences (no libm in loop) ----------
__global__ void fn_init(float* __restrict__ ws) {
    int tid = blockIdx.x * blockDim.x + threadIdx.x;
    if (tid < N_D) {
        int j = tid / KB, k = tid % KB;
        double x = -(double)(k * j) / 96.0;            // theta/pi
        ws[D_OFF + j * KP + 2 * k]     = (float)cospi(x);
        ws[D_OFF + j * KP + 2 * k + 1] = (float)sinpi(x);
    } else if (tid < N_D + N_E) {
        int t2 = tid - N_D;
        int t = t2 / KB, k = t2 % KB;
        double g = 0.01 / 97.0;
        double x = 2.0 * (double)(k * t) / 97.0;       // theta/pi
        ws[E_OFF + t * KP + 2 * k]     = (float)(g * (k == 0 ? 1.0 : 2.0) * cospi(x));
        ws[E_OFF + t * KP + 2 * k + 1] = (float)(k == 0 ? 0.0 : -2.0 * g * sinpi(x));
    } else if (tid < N_ALL) {
        int t2 = tid - (N_D + N_E);
        int kap = t2 / KB, k = t2 % KB;
        // e(k,m) = exp(-2pi i k m/192); rotation step
        double sr_ = cospi(-(double)k / 96.0), si_ = sinpi(-(double)k / 96.0);
        double er = 1.0, ei = 0.0;
        // c(kap,m) = cos(2pi kap (m-64)/129), Chebyshev recurrence
        double C2 = 2.0 * cospi(2.0 * (double)kap / 129.0);
        double c_prev = cospi(-130.0 * (double)kap / 129.0);   // m = -1
        double c_cur  = cospi(-128.0 * (double)kap / 129.0);   // m = 0
        // u(m) = cos(2pi m/129) for the hann window
        double U2 = 2.0 * cospi(2.0 / 129.0);
        double u_prev = cospi(2.0 / 129.0);                    // u(-1)
        double u_cur  = 1.0;                                   // u(0)
        double accr = 0.0, acci = 0.0;
        for (int m = 0; m < 129; m++) {
            double win = 0.5 * (1.0 - u_cur);
            double a = win * (1.0 / 129.0);
            if (kap) a *= 2.0 * c_cur;
            accr += a * er; acci += a * ei;
            double un = U2 * u_cur - u_prev; u_prev = u_cur; u_cur = un;
            double cn = C2 * c_cur - c_prev; c_prev = c_cur; c_cur = cn;
            double e2r = er * sr_ - ei * si_;
            double e2i = er * si_ + ei * sr_;
            er = e2r; ei = e2i;
        }
        ws[W_OFF + kap * KP + 2 * k]     = (float)accr;
        ws[W_OFF + kap * KP + 2 * k + 1] = (float)acci;
    }
}

// 49-way repetition with LITERAL indices: hipcc's SROA runs before loop
// unrolling, so any array indexed by a source-level loop variable is demoted
// to scratch (rounds 1-4: VGPR=68, 182MB scratch write-back). Token-pasted
// named scalars are the only reliable way to keep X in VGPRs.
#define REP49(M) M(0) M(1) M(2) M(3) M(4) M(5) M(6) M(7) M(8) M(9) \
  M(10) M(11) M(12) M(13) M(14) M(15) M(16) M(17) M(18) M(19) \
  M(20) M(21) M(22) M(23) M(24) M(25) M(26) M(27) M(28) M(29) \
  M(30) M(31) M(32) M(33) M(34) M(35) M(36) M(37) M(38) M(39) \
  M(40) M(41) M(42) M(43) M(44) M(45) M(46) M(47) M(48)

// one k-tile of phase 3+4: R = (W.h) for 7 consecutive bins, then X *= R
#define P3TILE(k0,k1,k2,k3,k4,k5,k6) { \
    float Ar=0.f,Br=0.f,Cr=0.f,Dr=0.f,Pr=0.f,Fr=0.f,Gr=0.f; \
    float Ai=0.f,Bi=0.f,Ci=0.f,Di=0.f,Pi_=0.f,Fi=0.f,Gi=0.f; \
    for (int kap = 0; kap < FC; kap++) { \
        float h = bufA[L * FC + kap]; \
        const float* w = ws + W_OFF + kap * KP; \
        Ar=fmaf(h,w[2*k0],Ar);   Ai=fmaf(h,w[2*k0+1],Ai); \
        Br=fmaf(h,w[2*k1],Br);   Bi=fmaf(h,w[2*k1+1],Bi); \
        Cr=fmaf(h,w[2*k2],Cr);   Ci=fmaf(h,w[2*k2+1],Ci); \
        Dr=fmaf(h,w[2*k3],Dr);   Di=fmaf(h,w[2*k3+1],Di); \
        Pr=fmaf(h,w[2*k4],Pr);   Pi_=fmaf(h,w[2*k4+1],Pi_); \
        Fr=fmaf(h,w[2*k5],Fr);   Fi=fmaf(h,w[2*k5+1],Fi); \
        Gr=fmaf(h,w[2*k6],Gr);   Gi=fmaf(h,w[2*k6+1],Gi); \
    } \
    { float xr_; \
      xr_ = Nr##k0*Ar - Ni##k0*Ai;  Ni##k0 = Nr##k0*Ai  + Ni##k0*Ar; Nr##k0 = xr_; \
      xr_ = Nr##k1*Br - Ni##k1*Bi;  Ni##k1 = Nr##k1*Bi  + Ni##k1*Br; Nr##k1 = xr_; \
      xr_ = Nr##k2*Cr - Ni##k2*Ci;  Ni##k2 = Nr##k2*Ci  + Ni##k2*Cr; Nr##k2 = xr_; \
      xr_ = Nr##k3*Dr - Ni##k3*Di;  Ni##k3 = Nr##k3*Di  + Ni##k3*Dr; Nr##k3 = xr_; \
      xr_ = Nr##k4*Pr - Ni##k4*Pi_; Ni##k4 = Nr##k4*Pi_ + Ni##k4*Pr; Nr##k4 = xr_; \
      xr_ = Nr##k5*Fr - Ni##k5*Fi;  Ni##k5 = Nr##k5*Fi  + Ni##k5*Fr; Nr##k5 = xr_; \
      xr_ = Nr##k6*Gr - Ni##k6*Gi;  Ni##k6 = Nr##k6*Gi  + Ni##k6*Gr; Nr##k6 = xr_; } \
}

// ---------- main: 1 wave/block, 64 frames (63 output + 1 redundant) ----------
__launch_bounds__(64, 2)
__global__ void fn_main_kernel(const float* __restrict__ H,
                               const float* __restrict__ noise,
                               const float* __restrict__ ws,
                               float* __restrict__ out) {
    __shared__ float bufA[64 * 65];       // 16.6 KB, reused: noise -> H -> obuf

    int bid = blockIdx.x;
    int b = bid >> 6;                     // NCHUNK = 64
    int c = bid & 63;
    int f0 = c * CHUNK;
    int nf = min(CHUNK, F_ - f0);
    int L = threadIdx.x;                  // lane computes frame f0-1+L
    int fMine = f0 - 1 + L;

    // ---- phase 0: stage noise frames f0-1 .. f0+62 (row i, stride 65) ----
    long nbase = ((long)b * F_ + (f0 - 1)) * FRAME;
    const long nmax = (long)B_ * F_ * FRAME - 1;
#pragma unroll 1
    for (int i = 0; i < 64; i++) {
        long g = nbase + (long)i * 64 + L;
        g = g < 0 ? 0 : (g > nmax ? nmax : g);
        float v = 2.0f * noise[g] - 1.0f;
        if (c == 0 && i == 0) v = 0.0f;   // frame -1: force N=0 -> X=0
        bufA[i * 65 + L] = v;
    }
    __syncthreads();

    // ---- X state: 98 named scalar registers ----
#define DECLX(k) float Nr##k = 0.0f, Ni##k = 0.0f;
    REP49(DECLX)
#undef DECLX

    // ---- phase 1: N[k] = DFT_192 of my frame (bins 0..48) ----
#pragma unroll 1
    for (int j = 0; j < 64; j++) {
        float n = bufA[L * 65 + j];
        const float* d = ws + D_OFF + j * KP;
#define P1(k) Nr##k = fmaf(n, d[2*k], Nr##k); Ni##k = fmaf(n, d[2*k+1], Ni##k);
        REP49(P1)
#undef P1
    }
    __syncthreads();

    // ---- phase 2: stage H (straight linear copy; 64 frames x 65 floats) ----
    long hbase = ((long)b * F_ + (f0 - 1)) * FC;
    const long hmax = (long)B_ * F_ * FC - 1;
#pragma unroll 1
    for (int i = 0; i < 65; i++) {
        long g = hbase + (long)i * 64 + L;
        g = g < 0 ? 0 : (g > hmax ? hmax : g);
        bufA[i * 64 + L] = H[g];
    }
    __syncthreads();

    // ---- phase 3+4: R = W.h per 7-bin tile, X = N*R in place ----
    P3TILE(0,1,2,3,4,5,6)
    P3TILE(7,8,9,10,11,12,13)
    P3TILE(14,15,16,17,18,19,20)
    P3TILE(21,22,23,24,25,26,27)
    P3TILE(28,29,30,31,32,33,34)
    P3TILE(35,36,37,38,39,40,41)
    P3TILE(42,43,44,45,46,47,48)
    __syncthreads();                      // H dead; bufA becomes obuf (stride 65)

    // ---- phase 5: y[t] = E[t].X ; overlap-add resolved in-wave via obuf RMW ----
    // ya[] has only constant-folded literal indices -> stays in registers
#define P5(k) ya[(k) & 3]       = fmaf(Nr##k, e[2*k],   ya[(k) & 3]); \
              ya[((k) + 2) & 3] = fmaf(Ni##k, e[2*k+1], ya[((k) + 2) & 3]);
#pragma unroll 1
    for (int t = 0; t < 64; t++) {
        const float* e = ws + E_OFF + t * KP;
        float ya[4] = {0.f, 0.f, 0.f, 0.f};
        REP49(P5)
        float y = (ya[0] + ya[1]) + (ya[2] + ya[3]);
        if (L) bufA[(L - 1) * 65 + t] = y;
    }
#pragma unroll 1
    for (int t = 64; t < 97; t++) {
        const float* e = ws + E_OFF + t * KP;
        float ya[4] = {0.f, 0.f, 0.f, 0.f};
        REP49(P5)
        float y = (ya[0] + ya[1]) + (ya[2] + ya[3]);

        int r = t - 64;
        float p = __shfl_up(y, 1);                    // prev frame's tail sample
        if (L) bufA[(L - 1) * 65 + r] += p;           // head + prev tail
        if (fMine == F_ - 1)                          // global last frame's tail
            out[(long)b * OUT_LEN + (long)(F_ - 1) * FRAME + t] = y;
    }
#undef P5
    __syncthreads();

    // ---- phase 6: coalesced 256B wave stores ----
    long obase2 = (long)b * OUT_LEN + (long)f0 * FRAME;
#pragma unroll 1
    for (int i = 0; i < nf; i++) {
        out[obase2 + (long)i * 64 + L] = bufA[i * 65 + L];
    }
}

extern "C" void kernel_launch(void* const* d_in, const int* in_sizes, int n_in,
                              void* d_out, int out_size, void* d_ws, size_t ws_size,
                              hipStream_t stream) {
    const float* H     = (const float*)d_in[0];   // (32, 4000, 65) fp32
    const float* noise = (const float*)d_in[1];   // (32, 4000, 64) fp32
    float* out = (float*)d_out;                   // (32, 256033) fp32
    float* ws  = (float*)d_ws;                    // matrices, 22148 floats

    fn_init<<<(N_ALL + 255) / 256, 256, 0, stream>>>(ws);
    fn_main_kernel<<<B_ * NCHUNK, 64, 0, stream>>>(H, noise, ws, out);
}